// Round 3
// baseline (134.923 us; speedup 1.0000x reference)
//
#include <hip/hip_runtime.h>
#include <hip/hip_bf16.h>
#include <stdint.h>
#include <stddef.h>

#define BATCH 4
#define SEQ   2048
#define DM    512
#define NST   64
#define LN_EPS 1e-5f

typedef __attribute__((ext_vector_type(8))) short short8;
typedef __attribute__((ext_vector_type(4))) float f32x4;

// quad_perm DPP: xor-1 = [1,0,3,2] = 0xB1, xor-2 = [2,3,0,1] = 0x4E (VALU pipe, stays in LDS-free lane quads)
#define DPP_XOR1(x) __int_as_float(__builtin_amdgcn_mov_dpp(__float_as_int(x), 0xB1, 0xF, 0xF, true))
#define DPP_XOR2(x) __int_as_float(__builtin_amdgcn_mov_dpp(__float_as_int(x), 0x4E, 0xF, 0xF, true))

// ---------------- Kernel 0: precompute per-(d,s) scan constants + W -> bf16 ----------------
__global__ __launch_bounds__(256) void k_pre(
    const float* __restrict__ logA, const float* __restrict__ Aim,
    const float* __restrict__ Bp, const float* __restrict__ Cp,
    const float* __restrict__ W,
    float4* __restrict__ c0, __hip_bfloat16* __restrict__ Wbf)
{
    int i = blockIdx.x * 256 + threadIdx.x;
    if (i < DM * DM) Wbf[i] = __float2bfloat16(W[i]);
    if (i < DM * NST) {
        float a = expf(logA[i]);          // decay rate, > 0
        float wim = Aim[i];
        float mag = expf(-a);             // |e^A|
        float er = mag * cosf(wim);
        float ei = mag * sinf(wim);
        float Br = Bp[2*i], Bi = Bp[2*i+1];
        float Cr = Cp[2*i], Ci = Cp[2*i+1];
        // conj(C)*B
        float CBr = Cr*Br + Ci*Bi;
        float CBi = Cr*Bi - Ci*Br;
        c0[i] = make_float4(er, ei, CBr, CBi);
    }
}

// ---------------- Kernel 1: backward SSM scan (LDS-lean v2) ----------------
// y[b,l,d] = D[d]*x[b,l,d] + Re( sum_s g_s[l] ),  g[l] = CB*x[l] + eA*g[l+1]
// grid: 256 blocks (b, d-group of 8). block: 512 thr = 8 waves; wave w -> d, lane -> state s.
// LDS discipline: cs round-trip uses only b128 ops (16 wr + 16 rd per chunk per wave);
// 4x4 in-register quad transpose via DPP moves the scatter off the LDS pipe.
__global__ __launch_bounds__(512) void k_scan(
    const float* __restrict__ x, const float4* __restrict__ c0,
    const float* __restrict__ Dp, __hip_bfloat16* __restrict__ ybf)
{
    __shared__ float cs[8][64][64];   // 128 KiB: per-wave [l][s] tile, 16B-chunk XOR swizzle by (l&15)
    __shared__ float xb[2][64][9];    // double-buffered x stage / y transpose (pad 9)

    const int tid  = threadIdx.x;
    const int w    = tid >> 6;
    const int lane = tid & 63;
    const int b    = blockIdx.x >> 6;
    const int dg   = blockIdx.x & 63;
    const int d    = dg * 8 + w;

    const float4 cc = c0[d * NST + lane];
    const float er = cc.x, ei = cc.y, CBr = cc.z, CBi = cc.w;
    const float Dd = Dp[d];

    const float* xp = x + (size_t)b * SEQ * DM + dg * 8;
    __hip_bfloat16* yp = ybf + (size_t)b * SEQ * DM + dg * 8;

    const int sl = tid >> 3, sd = tid & 7;   // staging coords (64 l x 8 d)
    float* csw = &cs[w][0][0];
    const int qk = lane >> 2;                // state-quad chunk index for writes

    float gr = 0.f, gi = 0.f;                // state carries across chunks (backward)

    // prefetch first (highest) chunk
    float xpre = xp[((SEQ - 64) + sl) * DM + sd];

    for (int ch = SEQ / 64 - 1; ch >= 0; --ch) {
        const int pb = ch & 1;
        const int l0 = ch * 64;

        xb[pb][sl][sd] = xpre;
        __syncthreads();
        float xreg = xb[pb][lane][w];        // lane j holds x[l0+j] for this wave's d
        __syncthreads();
        if (ch > 0)                           // prefetch next chunk; latency hides under scan
            xpre = xp[((l0 - 64) + sl) * DM + sd];

        // backward scan, 16 groups of 4 steps; x broadcast via readlane (SGPR operand)
        #pragma unroll
        for (int gidx = 0; gidx < 16; ++gidx) {
            const int base = 60 - gidx * 4;
            float v0, v1, v2, v3;
            #pragma unroll
            for (int j = 3; j >= 0; --j) {
                const int i = base + j;
                float xv = __uint_as_float(
                    __builtin_amdgcn_readlane(__float_as_uint(xreg), i));
                float u0 = CBr * xv;
                float u1 = CBi * xv;
                float t  = fmaf(ei, gr, u1);               // uses old gr
                gr = fmaf(er, gr, fmaf(-ei, gi, u0));      // uses old gr, old gi
                gi = fmaf(er, gi, t);
                if (j == 3) v3 = gr; else if (j == 2) v2 = gr;
                else if (j == 1) v1 = gr; else v0 = gr;
            }
            // 4x4 quad transpose: M[q][j] = state(4k+q) at step base+j  ->  lane 4k+q holds
            // states 4k..4k+3 at step base+q in (a0..a3)
            float a0 = v0, a1 = v1, a2 = v2, a3 = v3;
            const bool o1 = lane & 1, o2 = lane & 2;
            float t01 = o1 ? a0 : a1;  t01 = DPP_XOR1(t01);
            a0 = o1 ? t01 : a0;        a1 = o1 ? a1 : t01;
            float t23 = o1 ? a2 : a3;  t23 = DPP_XOR1(t23);
            a2 = o1 ? t23 : a2;        a3 = o1 ? a3 : t23;
            float t02 = o2 ? a0 : a2;  t02 = DPP_XOR2(t02);
            a0 = o2 ? t02 : a0;        a2 = o2 ? a2 : t02;
            float t13 = o2 ? a1 : a3;  t13 = DPP_XOR2(t13);
            a1 = o2 ? t13 : a1;        a3 = o2 ? a3 : t13;

            const int row = base + (lane & 3);
            f32x4 vec = { a0, a1, a2, a3 };
            *(f32x4*)(csw + row * 64 + ((qk ^ (row & 15)) << 2)) = vec;   // one b128 per 4 steps
        }

        // reduce over s: lane j sums row j via 16 swizzled b128 reads
        f32x4 accv = { 0.f, 0.f, 0.f, 0.f };
        #pragma unroll
        for (int cb = 0; cb < 16; ++cb)
            accv += *(const f32x4*)(csw + lane * 64 + ((cb ^ (lane & 15)) << 2));
        float acc = (accv[0] + accv[1]) + (accv[2] + accv[3]);

        float yv = acc + Dd * xreg;          // + D*x skip term

        // transpose via LDS so global write is [l][d]-contiguous
        xb[pb][lane][w] = yv;
        __syncthreads();
        yp[(l0 + sl) * DM + sd] = __float2bfloat16(xb[pb][sl][sd]);
        // next iteration stages the other buffer; its barriers order the reuse
    }
}

// ---------------- Kernel 2: fused out_proj GEMM (bf16 MFMA) + residual + LayerNorm ----------------
// out[r][o] = LN_o( b_out[o] + sum_d y[r][d]*W[o][d] + x[r][o] ),  r = b*SEQ+l in [0,8192)
// grid: 256 blocks of 32 rows x full 512 cols. 256 thr = 4 waves (wave w -> cols w*128..+127).
__global__ __launch_bounds__(256) void k_gemm_ln(
    const __hip_bfloat16* __restrict__ ybf, const __hip_bfloat16* __restrict__ Wbf,
    const float* __restrict__ x, const float* __restrict__ bout,
    const float* __restrict__ gamma, const float* __restrict__ beta,
    float* __restrict__ out)
{
    __shared__ short As[32][32];      // y tile [row][k], 16B-chunk XOR swizzle
    __shared__ short Bs[512][32];     // W tile [o][k],   16B-chunk XOR swizzle
    __shared__ float red[4][32][2];   // per-wave row partials (sum, sumsq)
    __shared__ float stats[32][2];    // per-row (mu, rstd)

    const int tid  = threadIdx.x;
    const int w    = tid >> 6;
    const int lane = tid & 63;
    const int q    = lane >> 4;       // k-block / row-quad selector
    const int m    = lane & 15;       // row (A) / col (B,C)
    const int r0   = blockIdx.x * 32;

    f32x4 acc[2][8];
    #pragma unroll
    for (int a = 0; a < 2; ++a)
        #pragma unroll
        for (int n = 0; n < 8; ++n)
            #pragma unroll
            for (int k = 0; k < 4; ++k) acc[a][n][k] = 0.f;

    for (int k0 = 0; k0 < DM; k0 += 32) {
        __syncthreads();
        // stage A: 32 rows x 32 k (bf16), 16B per thread
        if (tid < 128) {
            int row = tid >> 2, j = tid & 3;
            short8 v = *(const short8*)(ybf + (size_t)(r0 + row) * DM + k0 + j * 8);
            *(short8*)&As[row][(j ^ (row & 3)) * 8] = v;
        }
        // stage B: 512 rows(o) x 32 k
        #pragma unroll
        for (int it = 0; it < 8; ++it) {
            int o = it * 64 + (tid >> 2), j = tid & 3;
            short8 v = *(const short8*)(Wbf + (size_t)o * DM + k0 + j * 8);
            *(short8*)&Bs[o][(j ^ (o & 3)) * 8] = v;
        }
        __syncthreads();

        // A frag: lane holds A[m][ (q^swz)*8 .. +8 ]
        short8 a0 = *(const short8*)&As[m][(q ^ (m & 3)) * 8];
        short8 a1 = *(const short8*)&As[16 + m][(q ^ (m & 3)) * 8];
        #pragma unroll
        for (int nf = 0; nf < 8; ++nf) {
            int o = w * 128 + nf * 16 + m;          // o&3 == m&3
            short8 bb = *(const short8*)&Bs[o][(q ^ (m & 3)) * 8];
            acc[0][nf] = __builtin_amdgcn_mfma_f32_16x16x32_bf16(a0, bb, acc[0][nf], 0, 0, 0);
            acc[1][nf] = __builtin_amdgcn_mfma_f32_16x16x32_bf16(a1, bb, acc[1][nf], 0, 0, 0);
        }
    }

    // ---- epilogue: +bias, +x residual, row mean/var, normalize ----
    float bo[8], ga[8], be[8];
    #pragma unroll
    for (int nf = 0; nf < 8; ++nf) {
        int o = w * 128 + nf * 16 + m;
        bo[nf] = bout[o]; ga[nf] = gamma[o]; be[nf] = beta[o];
    }

    float rs[2][4], rq[2][4];
    #pragma unroll
    for (int mf = 0; mf < 2; ++mf)
        #pragma unroll
        for (int i = 0; i < 4; ++i) { rs[mf][i] = 0.f; rq[mf][i] = 0.f; }

    #pragma unroll
    for (int mf = 0; mf < 2; ++mf)
        #pragma unroll
        for (int nf = 0; nf < 8; ++nf) {
            int o = w * 128 + nf * 16 + m;
            #pragma unroll
            for (int i = 0; i < 4; ++i) {
                int row = mf * 16 + q * 4 + i;     // C/D: row=(lane>>4)*4+reg, col=lane&15
                float zv = acc[mf][nf][i] + bo[nf] + x[(size_t)(r0 + row) * DM + o];
                acc[mf][nf][i] = zv;               // keep z in acc regs
                rs[mf][i] += zv;
                rq[mf][i] += zv * zv;
            }
        }

    // reduce across the 16 lanes (m) sharing each row
    #pragma unroll
    for (int mask = 1; mask < 16; mask <<= 1) {
        #pragma unroll
        for (int mf = 0; mf < 2; ++mf)
            #pragma unroll
            for (int i = 0; i < 4; ++i) {
                rs[mf][i] += __shfl_xor(rs[mf][i], mask);
                rq[mf][i] += __shfl_xor(rq[mf][i], mask);
            }
    }
    if (m == 0) {
        #pragma unroll
        for (int mf = 0; mf < 2; ++mf)
            #pragma unroll
            for (int i = 0; i < 4; ++i) {
                int row = mf * 16 + q * 4 + i;
                red[w][row][0] = rs[mf][i];
                red[w][row][1] = rq[mf][i];
            }
    }
    __syncthreads();
    if (tid < 32) {
        float s = 0.f, sq = 0.f;
        #pragma unroll
        for (int ww = 0; ww < 4; ++ww) { s += red[ww][tid][0]; sq += red[ww][tid][1]; }
        float mu  = s * (1.f / DM);
        float var = sq * (1.f / DM) - mu * mu;
        stats[tid][0] = mu;
        stats[tid][1] = 1.f / sqrtf(var + LN_EPS);
    }
    __syncthreads();

    #pragma unroll
    for (int mf = 0; mf < 2; ++mf)
        #pragma unroll
        for (int i = 0; i < 4; ++i) {
            int row = mf * 16 + q * 4 + i;
            float mu = stats[row][0], rstd = stats[row][1];
            #pragma unroll
            for (int nf = 0; nf < 8; ++nf) {
                int o = w * 128 + nf * 16 + m;
                out[(size_t)(r0 + row) * DM + o] =
                    ga[nf] * (acc[mf][nf][i] - mu) * rstd + be[nf];
            }
        }
}

// ---------------- launcher ----------------
extern "C" void kernel_launch(void* const* d_in, const int* in_sizes, int n_in,
                              void* d_out, int out_size, void* d_ws, size_t ws_size,
                              hipStream_t stream)
{
    const float* x    = (const float*)d_in[0];
    const float* logA = (const float*)d_in[1];
    const float* Aim  = (const float*)d_in[2];
    const float* Bp   = (const float*)d_in[3];
    const float* Cp   = (const float*)d_in[4];
    const float* Dp   = (const float*)d_in[5];
    const float* W    = (const float*)d_in[6];
    const float* bo   = (const float*)d_in[7];
    const float* ga   = (const float*)d_in[8];
    const float* be   = (const float*)d_in[9];

    char* ws = (char*)d_ws;
    float4* c0          = (float4*)ws;                          // 512 KiB
    __hip_bfloat16* Wbf = (__hip_bfloat16*)(ws + (512 << 10));  // 512 KiB
    __hip_bfloat16* ybf = (__hip_bfloat16*)(ws + (1 << 20));    // 8 MiB

    k_pre<<<(DM * DM + 255) / 256, 256, 0, stream>>>(logA, Aim, Bp, Cp, W, c0, Wbf);
    k_scan<<<BATCH * (DM / 8), 512, 0, stream>>>(x, c0, Dp, ybf);
    k_gemm_ln<<<(BATCH * SEQ) / 32, 256, 0, stream>>>(ybf, Wbf, x, bo, ga, be, (float*)d_out);
}

// Round 4
// 108.771 us; speedup vs baseline: 1.2404x; 1.2404x over previous
//
#include <hip/hip_runtime.h>
#include <hip/hip_bf16.h>
#include <stdint.h>
#include <stddef.h>

#define BATCH 4
#define SEQ   2048
#define DM    512
#define NST   64
#define LN_EPS 1e-5f

typedef __attribute__((ext_vector_type(8))) short short8;
typedef __attribute__((ext_vector_type(4))) float f32x4;

// ---------------- Kernel 0: precompute per-(d,s) scan constants + W -> bf16 ----------------
__global__ __launch_bounds__(256) void k_pre(
    const float* __restrict__ logA, const float* __restrict__ Aim,
    const float* __restrict__ Bp, const float* __restrict__ Cp,
    const float* __restrict__ W,
    float4* __restrict__ c0, __hip_bfloat16* __restrict__ Wbf)
{
    int i = blockIdx.x * 256 + threadIdx.x;
    if (i < DM * DM) Wbf[i] = __float2bfloat16(W[i]);
    if (i < DM * NST) {
        float a = expf(logA[i]);          // decay rate, > 0
        float wim = Aim[i];
        float mag = expf(-a);             // |e^A|
        float er = mag * cosf(wim);
        float ei = mag * sinf(wim);
        float Br = Bp[2*i], Bi = Bp[2*i+1];
        float Cr = Cp[2*i], Ci = Cp[2*i+1];
        // conj(C)*B
        float CBr = Cr*Br + Ci*Bi;
        float CBi = Cr*Bi - Ci*Br;
        c0[i] = make_float4(er, ei, CBr, CBi);
    }
}

// ---------------- Kernel 1: backward SSM scan (stall-lean v4) ----------------
// y[b,l,d] = D[d]*x[b,l,d] + Re( sum_s g_s[l] ),  g[l] = CB*x[l] + eA*g[l+1]
// grid: 256 blocks (b, d-group of 8). block: 512 thr = 8 waves; wave w -> d, lane -> state s.
// v4: no x staging (per-wave gather, lane=l, prefetched); cs b32 scatter (conflict-free)
// + quad-rotated b128 reduce (broadcast within quads); 1 barrier/chunk (y transpose only).
__global__ __launch_bounds__(512) void k_scan(
    const float* __restrict__ x, const float4* __restrict__ c0,
    const float* __restrict__ Dp, __hip_bfloat16* __restrict__ ybf)
{
    __shared__ float cs[8][64][64];   // 128 KiB: per-wave [l][s] tile (wave-private, no barrier)
    __shared__ float yt[2][64][9];    // double-buffered y transpose (pad 9 -> conflict-free)

    const int tid  = threadIdx.x;
    const int w    = tid >> 6;
    const int lane = tid & 63;
    const int b    = blockIdx.x >> 6;
    const int dg   = blockIdx.x & 63;
    const int d    = dg * 8 + w;

    const float4 cc = c0[d * NST + lane];
    const float er = cc.x, ei = cc.y, CBr = cc.z, CBi = cc.w;
    const float Dd = Dp[d];

    const float* xcol = x + (size_t)b * SEQ * DM + d;          // per-wave column (lane = l)
    __hip_bfloat16* yp = ybf + (size_t)b * SEQ * DM + dg * 8;

    const int sl = tid >> 3, sd = tid & 7;   // output store coords (64 l x 8 d)
    float* csw = &cs[w][0][0];

    float gr = 0.f, gi = 0.f;                // state carries across chunks (backward)

    // prefetch first (highest) chunk: lane j -> x[SEQ-64+j][d]; 8 waves share 64B lines (L1)
    float xpre = xcol[(size_t)(SEQ - 64 + lane) * DM];

    for (int ch = SEQ / 64 - 1; ch >= 0; --ch) {
        const int pb = ch & 1;
        const int l0 = ch * 64;

        float xreg = xpre;                   // lane j holds x[l0+j] for this wave's d
        if (ch > 0)                          // prefetch next chunk; vmcnt hides under scan
            xpre = xcol[(size_t)(l0 - 64 + lane) * DM];

        // backward scan; x broadcast via readlane (SGPR operand), Re(g) scattered to cs.
        // write cs[w][i][lane]: bank = lane%32 -> 2-way (free).
        #pragma unroll
        for (int i = 63; i >= 0; --i) {
            float xv = __uint_as_float(
                __builtin_amdgcn_readlane(__float_as_uint(xreg), i));
            float u0 = CBr * xv;
            float u1 = CBi * xv;
            float t  = fmaf(ei, gr, u1);               // uses old gr
            gr = fmaf(er, gr, fmaf(-ei, gi, u0));      // uses old gr, old gi
            gi = fmaf(er, gi, t);
            csw[i * 64 + lane] = gr;                   // Re(g[l0+i]) for state s
        }

        // reduce over s: lane l sums row l via 16 quad-rotated b128 reads.
        // quad lanes share an address (LDS broadcast); 16 quads span 32 banks 2-way (free).
        const int cb0 = lane & ~3;
        f32x4 accv = { 0.f, 0.f, 0.f, 0.f };
        #pragma unroll
        for (int k = 0; k < 16; ++k)
            accv += *(const f32x4*)(csw + lane * 64 + ((cb0 + 4 * k) & 63));
        float acc = (accv[0] + accv[1]) + (accv[2] + accv[3]);

        float yv = acc + Dd * xreg;          // + D*x skip term (lane = l matches)

        // transpose via LDS so global write is [l][d]-contiguous; double-buffered ->
        // reuse of yt[pb] (chunk ch-2) is ordered by chunk ch-1's barrier.
        yt[pb][lane][w] = yv;
        __syncthreads();
        yp[(size_t)(l0 + sl) * DM + sd] = __float2bfloat16(yt[pb][sl][sd]);
    }
}

// ---------------- Kernel 2: fused out_proj GEMM (bf16 MFMA) + residual + LayerNorm ----------------
// out[r][o] = LN_o( b_out[o] + sum_d y[r][d]*W[o][d] + x[r][o] ),  r = b*SEQ+l in [0,8192)
// grid: 256 blocks of 32 rows x full 512 cols. 256 thr = 4 waves (wave w -> cols w*128..+127).
__global__ __launch_bounds__(256) void k_gemm_ln(
    const __hip_bfloat16* __restrict__ ybf, const __hip_bfloat16* __restrict__ Wbf,
    const float* __restrict__ x, const float* __restrict__ bout,
    const float* __restrict__ gamma, const float* __restrict__ beta,
    float* __restrict__ out)
{
    __shared__ short As[32][32];      // y tile [row][k], 16B-chunk XOR swizzle
    __shared__ short Bs[512][32];     // W tile [o][k],   16B-chunk XOR swizzle
    __shared__ float red[4][32][2];   // per-wave row partials (sum, sumsq)
    __shared__ float stats[32][2];    // per-row (mu, rstd)

    const int tid  = threadIdx.x;
    const int w    = tid >> 6;
    const int lane = tid & 63;
    const int q    = lane >> 4;       // k-block / row-quad selector
    const int m    = lane & 15;       // row (A) / col (B,C)
    const int r0   = blockIdx.x * 32;

    f32x4 acc[2][8];
    #pragma unroll
    for (int a = 0; a < 2; ++a)
        #pragma unroll
        for (int n = 0; n < 8; ++n)
            #pragma unroll
            for (int k = 0; k < 4; ++k) acc[a][n][k] = 0.f;

    for (int k0 = 0; k0 < DM; k0 += 32) {
        __syncthreads();
        // stage A: 32 rows x 32 k (bf16), 16B per thread
        if (tid < 128) {
            int row = tid >> 2, j = tid & 3;
            short8 v = *(const short8*)(ybf + (size_t)(r0 + row) * DM + k0 + j * 8);
            *(short8*)&As[row][(j ^ (row & 3)) * 8] = v;
        }
        // stage B: 512 rows(o) x 32 k
        #pragma unroll
        for (int it = 0; it < 8; ++it) {
            int o = it * 64 + (tid >> 2), j = tid & 3;
            short8 v = *(const short8*)(Wbf + (size_t)o * DM + k0 + j * 8);
            *(short8*)&Bs[o][(j ^ (o & 3)) * 8] = v;
        }
        __syncthreads();

        // A frag: lane holds A[m][ (q^swz)*8 .. +8 ]
        short8 a0 = *(const short8*)&As[m][(q ^ (m & 3)) * 8];
        short8 a1 = *(const short8*)&As[16 + m][(q ^ (m & 3)) * 8];
        #pragma unroll
        for (int nf = 0; nf < 8; ++nf) {
            int o = w * 128 + nf * 16 + m;          // o&3 == m&3
            short8 bb = *(const short8*)&Bs[o][(q ^ (m & 3)) * 8];
            acc[0][nf] = __builtin_amdgcn_mfma_f32_16x16x32_bf16(a0, bb, acc[0][nf], 0, 0, 0);
            acc[1][nf] = __builtin_amdgcn_mfma_f32_16x16x32_bf16(a1, bb, acc[1][nf], 0, 0, 0);
        }
    }

    // ---- epilogue: +bias, +x residual, row mean/var, normalize ----
    float bo[8], ga[8], be[8];
    #pragma unroll
    for (int nf = 0; nf < 8; ++nf) {
        int o = w * 128 + nf * 16 + m;
        bo[nf] = bout[o]; ga[nf] = gamma[o]; be[nf] = beta[o];
    }

    float rs[2][4], rq[2][4];
    #pragma unroll
    for (int mf = 0; mf < 2; ++mf)
        #pragma unroll
        for (int i = 0; i < 4; ++i) { rs[mf][i] = 0.f; rq[mf][i] = 0.f; }

    #pragma unroll
    for (int mf = 0; mf < 2; ++mf)
        #pragma unroll
        for (int nf = 0; nf < 8; ++nf) {
            int o = w * 128 + nf * 16 + m;
            #pragma unroll
            for (int i = 0; i < 4; ++i) {
                int row = mf * 16 + q * 4 + i;     // C/D: row=(lane>>4)*4+reg, col=lane&15
                float zv = acc[mf][nf][i] + bo[nf] + x[(size_t)(r0 + row) * DM + o];
                acc[mf][nf][i] = zv;               // keep z in acc regs
                rs[mf][i] += zv;
                rq[mf][i] += zv * zv;
            }
        }

    // reduce across the 16 lanes (m) sharing each row
    #pragma unroll
    for (int mask = 1; mask < 16; mask <<= 1) {
        #pragma unroll
        for (int mf = 0; mf < 2; ++mf)
            #pragma unroll
            for (int i = 0; i < 4; ++i) {
                rs[mf][i] += __shfl_xor(rs[mf][i], mask);
                rq[mf][i] += __shfl_xor(rq[mf][i], mask);
            }
    }
    if (m == 0) {
        #pragma unroll
        for (int mf = 0; mf < 2; ++mf)
            #pragma unroll
            for (int i = 0; i < 4; ++i) {
                int row = mf * 16 + q * 4 + i;
                red[w][row][0] = rs[mf][i];
                red[w][row][1] = rq[mf][i];
            }
    }
    __syncthreads();
    if (tid < 32) {
        float s = 0.f, sq = 0.f;
        #pragma unroll
        for (int ww = 0; ww < 4; ++ww) { s += red[ww][tid][0]; sq += red[ww][tid][1]; }
        float mu  = s * (1.f / DM);
        float var = sq * (1.f / DM) - mu * mu;
        stats[tid][0] = mu;
        stats[tid][1] = 1.f / sqrtf(var + LN_EPS);
    }
    __syncthreads();

    #pragma unroll
    for (int mf = 0; mf < 2; ++mf)
        #pragma unroll
        for (int i = 0; i < 4; ++i) {
            int row = mf * 16 + q * 4 + i;
            float mu = stats[row][0], rstd = stats[row][1];
            #pragma unroll
            for (int nf = 0; nf < 8; ++nf) {
                int o = w * 128 + nf * 16 + m;
                out[(size_t)(r0 + row) * DM + o] =
                    ga[nf] * (acc[mf][nf][i] - mu) * rstd + be[nf];
            }
        }
}

// ---------------- launcher ----------------
extern "C" void kernel_launch(void* const* d_in, const int* in_sizes, int n_in,
                              void* d_out, int out_size, void* d_ws, size_t ws_size,
                              hipStream_t stream)
{
    const float* x    = (const float*)d_in[0];
    const float* logA = (const float*)d_in[1];
    const float* Aim  = (const float*)d_in[2];
    const float* Bp   = (const float*)d_in[3];
    const float* Cp   = (const float*)d_in[4];
    const float* Dp   = (const float*)d_in[5];
    const float* W    = (const float*)d_in[6];
    const float* bo   = (const float*)d_in[7];
    const float* ga   = (const float*)d_in[8];
    const float* be   = (const float*)d_in[9];

    char* ws = (char*)d_ws;
    float4* c0          = (float4*)ws;                          // 512 KiB
    __hip_bfloat16* Wbf = (__hip_bfloat16*)(ws + (512 << 10));  // 512 KiB
    __hip_bfloat16* ybf = (__hip_bfloat16*)(ws + (1 << 20));    // 8 MiB

    k_pre<<<(DM * DM + 255) / 256, 256, 0, stream>>>(logA, Aim, Bp, Cp, W, c0, Wbf);
    k_scan<<<BATCH * (DM / 8), 512, 0, stream>>>(x, c0, Dp, ybf);
    k_gemm_ln<<<(BATCH * SEQ) / 32, 256, 0, stream>>>(ybf, Wbf, x, bo, ga, be, (float*)d_out);
}